// Round 5
// baseline (11937.930 us; speedup 1.0000x reference)
//
#include <hip/hip_runtime.h>

#define Bn 64
#define Sn 512
#define Fn 64
#define Hn 512
#define Un 128
#define Tn 96

typedef __attribute__((ext_vector_type(8))) short bf16x8;
typedef __attribute__((ext_vector_type(4))) float f32x4;
typedef unsigned int u32;
typedef unsigned long long u64;

#define MFMA16(a, b, c) __builtin_amdgcn_mfma_f32_16x16x32_bf16(a, b, c, 0, 0, 0)
#define ALOAD64(p) __hip_atomic_load((p), __ATOMIC_RELAXED, __HIP_MEMORY_SCOPE_AGENT)

__device__ __forceinline__ float sigm(float x) { return 1.0f / (1.0f + __expf(-x)); }
__device__ __forceinline__ float tanh_f(float x) {
    x = fminf(fmaxf(x, -15.0f), 15.0f);
    float e = __expf(2.0f * x);
    return (e - 1.0f) / (e + 1.0f);
}
__device__ __forceinline__ short bf16rtn(float f) {
    unsigned u = __float_as_uint(f);
    unsigned r = (u + 0x7FFFu + ((u >> 16) & 1u)) >> 16;
    return (short)r;
}
__device__ __forceinline__ float bf16tof(short s) {
    return __uint_as_float(((unsigned)(unsigned short)s) << 16);
}

// ============================ setup kernels ============================
__global__ __launch_bounds__(256) void k_split_x(const float* __restrict__ x,
                                                 short* __restrict__ xhi, short* __restrict__ xlo) {
    int t = blockIdx.x * 256 + threadIdx.x;          // 2,097,152 = B*S*F
    int f = t & 63, s = (t >> 6) & 511, b = t >> 15;
    float v = x[t];
    short hi = bf16rtn(v);
    short lo = bf16rtn(v - bf16tof(hi));
    int o = (s * Bn + b) * Fn + f;                   // x[s][b][f]
    xhi[o] = hi; xlo[o] = lo;
}
__global__ __launch_bounds__(256) void k_split_whh(const float* __restrict__ w,
                                                   short* __restrict__ whi, short* __restrict__ wlo) {
    int t = blockIdx.x * 256 + threadIdx.x;          // 1,048,576
    int k = t & 511, r = t >> 9;                     // r = g*512+j
    int g = r >> 9, j = r & 511;
    float v = w[t];
    short hi = bf16rtn(v);
    short lo = bf16rtn(v - bf16tof(hi));
    int o = (j * 4 + g) * 512 + k;                   // row' = j*4+g
    whi[o] = hi; wlo[o] = lo;
}
__global__ __launch_bounds__(256) void k_split_wih(const float* __restrict__ w,
                                                   short* __restrict__ whi, short* __restrict__ wlo) {
    int t = blockIdx.x * 256 + threadIdx.x;          // 131,072
    int k = t & 63, r = t >> 6;
    int g = r >> 9, j = r & 511;
    float v = w[t];
    short hi = bf16rtn(v);
    short lo = bf16rtn(v - bf16tof(hi));
    int o = (j * 4 + g) * 64 + k;
    whi[o] = hi; wlo[o] = lo;
}
__global__ __launch_bounds__(256) void k_bias_perm(const float* __restrict__ bih,
                                                   const float* __restrict__ bhh,
                                                   float* __restrict__ bperm) {
    int t = blockIdx.x * 256 + threadIdx.x;          // 2048
    int g = t >> 9, j = t & 511;
    bperm[j * 4 + g] = bih[t] + bhh[t];
}
__global__ __launch_bounds__(256) void k_w1t(const float* __restrict__ W1, float* __restrict__ W1T) {
    int t = blockIdx.x * 256 + threadIdx.x;          // 65,536 = U*H
    int u = t >> 9, k = t & 511;
    W1T[k * Un + u] = W1[t];
}
__global__ __launch_bounds__(256) void k_w2t_bf16(const float* __restrict__ W2, short* __restrict__ W2Tb) {
    int t = blockIdx.x * 256 + threadIdx.x;          // 65,536 = U*H
    int u = t >> 9, j = t & 511;
    W2Tb[j * Un + u] = bf16rtn(W2[t]);
}
__global__ __launch_bounds__(256) void k_transpose_dec(const float* __restrict__ dW, float* __restrict__ WiT,
                                                       float* __restrict__ WgT, float* __restrict__ WoT) {
    int t = blockIdx.x * 256 + threadIdx.x;          // 262,144 ; dec_Wih rows length 513
    int j = t & 511, j2 = t >> 9;
    WiT[t] = dW[(j)        * 513 + j2];              // WiT[k=j2][j]
    WgT[t] = dW[(1024 + j) * 513 + j2];
    WoT[t] = dW[(1536 + j) * 513 + j2];
}
// zero: hPk [2][32768] u32 + flags 512 u32 (contiguous 66048 u32) + sumE 6144 f32
__global__ __launch_bounds__(256) void k_zero_state(u32* __restrict__ z, float* __restrict__ se) {
    int t = blockIdx.x * 256 + threadIdx.x;          // 72,192 = 282*256
    if (t < 66048) z[t] = 0u;
    else se[t - 66048] = 0.0f;
}

// ============================ persistent encoder v3 ============================
// 32 blocks x 256 threads, 1 block/CU (133 KB LDS), guaranteed co-resident.
// Block owns output rows blk*64..+64 (rows = j*4+g -> j in blk*16..+16), all 64 b.
// Wave wv: 32x32 quadrant: rows rtB=(wv>>1)*32, cols ctB=(wv&1)*32; K=512 full.
// Per step: (1) all threads atomic-load packed h slot (coalesced) -> unpack ->
// LDS hi/lo arrays (stride 520 shorts: conflict-free b128 writes AND reads);
// (2) MFMA: A (Whh hi/lo) streamed from L2 (256KB/block, resident), B from LDS,
// bf16x3 = AhiBh + AhiBl + AloBh; x-part from hoisted wih A-frags + early-issued
// global x loads; (3) epilogue in-register (cst in VGPR), packed u32 atomic
// h-stores; (4) flags barrier: __syncthreads drains vmcnt, tid0 stores flag,
// wave0 polls all 32 flags.
__global__ __launch_bounds__(256, 1)
void enc_persist3(const short* __restrict__ xhi, const short* __restrict__ xlo,
                  const short* __restrict__ whhHi, const short* __restrict__ whhLo,
                  const short* __restrict__ wihHi, const short* __restrict__ wihLo,
                  const float* __restrict__ bperm,
                  u32* __restrict__ hPk, u32* __restrict__ flags,
                  short* __restrict__ encJ)
{
    __shared__ short hiL[64 * 520];
    __shared__ short loL[64 * 520];
    const int blk = blockIdx.x;
    const int tid = threadIdx.x;
    const int wv = tid >> 6, l = tid & 63;
    const int lr = l & 15, lk = l >> 4;
    const int rtB = (wv >> 1) * 32;
    const int ctB = (wv & 1) * 32;
    const int r0 = blk * 64 + rtB + lr;
    const int r1 = r0 + 16;
    const int b0 = ctB + lr, b1 = b0 + 16;

    // hoisted Wih A-frags [chunk][rowgrp][hi/lo]
    bf16x8 XA[2][2][2];
    #pragma unroll
    for (int cw = 0; cw < 2; cw++) {
        int k0 = cw * 32 + lk * 8;
        XA[cw][0][0] = *(const bf16x8*)(wihHi + r0 * 64 + k0);
        XA[cw][0][1] = *(const bf16x8*)(wihLo + r0 * 64 + k0);
        XA[cw][1][0] = *(const bf16x8*)(wihHi + r1 * 64 + k0);
        XA[cw][1][1] = *(const bf16x8*)(wihLo + r1 * 64 + k0);
    }
    const f32x4 bias0 = *(const f32x4*)(bperm + blk * 64 + rtB + lk * 4);
    const f32x4 bias1 = *(const f32x4*)(bperm + blk * 64 + rtB + 16 + lk * 4);
    float cst[2][2] = {{0.f, 0.f}, {0.f, 0.f}};

    #pragma unroll 1
    for (int t = 0; t < 512; t++) {
        const int pr = t & 1;
        // ---- x B-frags: issue early (cold HBM) ----
        bf16x8 XB[2][2][2];   // [chunk][colgrp][hi/lo]
        #pragma unroll
        for (int cw = 0; cw < 2; cw++) {
            int k0 = cw * 32 + lk * 8;
            XB[cw][0][0] = *(const bf16x8*)(xhi + ((size_t)t * 64 + b0) * 64 + k0);
            XB[cw][0][1] = *(const bf16x8*)(xlo + ((size_t)t * 64 + b0) * 64 + k0);
            XB[cw][1][0] = *(const bf16x8*)(xhi + ((size_t)t * 64 + b1) * 64 + k0);
            XB[cw][1][1] = *(const bf16x8*)(xlo + ((size_t)t * 64 + b1) * 64 + k0);
        }
        // ---- stage h(t-1) slot -> LDS (atomic loads, coalesced 2KB/wave) ----
        {
            const u32* src = hPk + pr * 32768;
            #pragma unroll 4
            for (int i = 0; i < 16; i++) {
                int idx = i * 2048 + tid * 8;
                const u64* q = (const u64*)(src + idx);
                u64 q0 = ALOAD64(q + 0);
                u64 q1 = ALOAD64(q + 1);
                u64 q2 = ALOAD64(q + 2);
                u64 q3 = ALOAD64(q + 3);
                u32 d0 = (u32)q0, d1 = (u32)(q0 >> 32);
                u32 d2 = (u32)q1, d3 = (u32)(q1 >> 32);
                u32 d4 = (u32)q2, d5 = (u32)(q2 >> 32);
                u32 d6 = (u32)q3, d7 = (u32)(q3 >> 32);
                union { bf16x8 v; u32 d[4]; } H, L;
                H.d[0] = (d0 >> 16) | (d1 & 0xFFFF0000u);
                L.d[0] = (d0 & 0xFFFFu) | (d1 << 16);
                H.d[1] = (d2 >> 16) | (d3 & 0xFFFF0000u);
                L.d[1] = (d2 & 0xFFFFu) | (d3 << 16);
                H.d[2] = (d4 >> 16) | (d5 & 0xFFFF0000u);
                L.d[2] = (d4 & 0xFFFFu) | (d5 << 16);
                H.d[3] = (d6 >> 16) | (d7 & 0xFFFF0000u);
                L.d[3] = (d6 & 0xFFFFu) | (d7 << 16);
                int bb = idx >> 9, kk = idx & 511;
                *(bf16x8*)(&hiL[bb * 520 + kk]) = H.v;
                *(bf16x8*)(&loL[bb * 520 + kk]) = L.v;
            }
        }
        __syncthreads();
        // ---- main K loop: 16 chunks of 32 ----
        f32x4 a00 = {0.f,0.f,0.f,0.f}, a01 = {0.f,0.f,0.f,0.f};
        f32x4 a10 = {0.f,0.f,0.f,0.f}, a11 = {0.f,0.f,0.f,0.f};
        #pragma unroll 4
        for (int c = 0; c < 16; c++) {
            int k0 = c * 32 + lk * 8;
            bf16x8 Ah0 = *(const bf16x8*)(whhHi + (size_t)r0 * 512 + k0);
            bf16x8 Al0 = *(const bf16x8*)(whhLo + (size_t)r0 * 512 + k0);
            bf16x8 Ah1 = *(const bf16x8*)(whhHi + (size_t)r1 * 512 + k0);
            bf16x8 Al1 = *(const bf16x8*)(whhLo + (size_t)r1 * 512 + k0);
            bf16x8 Bh0 = *(const bf16x8*)(&hiL[b0 * 520 + k0]);
            bf16x8 Bl0 = *(const bf16x8*)(&loL[b0 * 520 + k0]);
            bf16x8 Bh1 = *(const bf16x8*)(&hiL[b1 * 520 + k0]);
            bf16x8 Bl1 = *(const bf16x8*)(&loL[b1 * 520 + k0]);
            a00 = MFMA16(Ah0, Bh0, a00); a00 = MFMA16(Ah0, Bl0, a00); a00 = MFMA16(Al0, Bh0, a00);
            a01 = MFMA16(Ah0, Bh1, a01); a01 = MFMA16(Ah0, Bl1, a01); a01 = MFMA16(Al0, Bh1, a01);
            a10 = MFMA16(Ah1, Bh0, a10); a10 = MFMA16(Ah1, Bl0, a10); a10 = MFMA16(Al1, Bh0, a10);
            a11 = MFMA16(Ah1, Bh1, a11); a11 = MFMA16(Ah1, Bl1, a11); a11 = MFMA16(Al1, Bh1, a11);
        }
        // ---- x part ----
        #pragma unroll
        for (int cw = 0; cw < 2; cw++) {
            a00 = MFMA16(XA[cw][0][0], XB[cw][0][0], a00);
            a00 = MFMA16(XA[cw][0][0], XB[cw][0][1], a00);
            a00 = MFMA16(XA[cw][0][1], XB[cw][0][0], a00);
            a01 = MFMA16(XA[cw][0][0], XB[cw][1][0], a01);
            a01 = MFMA16(XA[cw][0][0], XB[cw][1][1], a01);
            a01 = MFMA16(XA[cw][0][1], XB[cw][1][0], a01);
            a10 = MFMA16(XA[cw][1][0], XB[cw][0][0], a10);
            a10 = MFMA16(XA[cw][1][0], XB[cw][0][1], a10);
            a10 = MFMA16(XA[cw][1][1], XB[cw][0][0], a10);
            a11 = MFMA16(XA[cw][1][0], XB[cw][1][0], a11);
            a11 = MFMA16(XA[cw][1][0], XB[cw][1][1], a11);
            a11 = MFMA16(XA[cw][1][1], XB[cw][1][0], a11);
        }
        // ---- epilogue: 4 (j,b) pairs per lane ----
        const int pw = 1 - pr;
        #pragma unroll
        for (int i = 0; i < 2; i++) {
            #pragma unroll
            for (int j = 0; j < 2; j++) {
                f32x4 A = (i == 0) ? ((j == 0) ? a00 : a01) : ((j == 0) ? a10 : a11);
                f32x4 bs = (i == 0) ? bias0 : bias1;
                float pi = A[0] + bs[0];
                float pf = A[1] + bs[1];
                float pg = A[2] + bs[2];
                float po = A[3] + bs[3];
                float ig = sigm(pi), fg = sigm(pf), gg = tanh_f(pg), og = sigm(po);
                float cn = fg * cst[i][j] + ig * gg;
                cst[i][j] = cn;
                float hv = og * tanh_f(cn);
                short hi16 = bf16rtn(hv);
                short lo16 = bf16rtn(hv - bf16tof(hi16));
                u32 pk = ((u32)(unsigned short)hi16 << 16) | (u32)(unsigned short)lo16;
                int jg = blk * 16 + (wv >> 1) * 8 + i * 4 + lk;
                int bb = ctB + j * 16 + lr;
                __hip_atomic_store(hPk + pw * 32768 + bb * 512 + jg, pk,
                                   __ATOMIC_RELAXED, __HIP_MEMORY_SCOPE_AGENT);
                encJ[(size_t)jg * (Sn * Bn) + t * 64 + bb] = hi16;
            }
        }
        // ---- barrier: drain all waves' stores, signal, poll 32 flags ----
        __syncthreads();                              // emits s_waitcnt vmcnt(0) before s_barrier
        if (tid == 0)
            __hip_atomic_store(&flags[blk * 16], (u32)(t + 1),
                               __ATOMIC_RELAXED, __HIP_MEMORY_SCOPE_AGENT);
        if (wv == 0) {
            while (true) {
                u32 v = (l < 32) ? __hip_atomic_load(&flags[l * 16], __ATOMIC_RELAXED,
                                                     __HIP_MEMORY_SCOPE_AGENT)
                                 : 0xFFFFFFFFu;
                if (__all(v > (u32)t)) break;
                __builtin_amdgcn_s_sleep(2);
            }
        }
        __syncthreads();
    }
}

// ============================ w2_enc GEMM (bf16 in/out) ============================
__global__ __launch_bounds__(256)
void w2enc_k(const short* __restrict__ encJ, const short* __restrict__ W2Tb,
             const float* __restrict__ b2, short* __restrict__ w2eb)
{
    __shared__ float tile[64 * 64];
    const int s = blockIdx.x;
    const int tid = threadIdx.x;
    const int u = tid & 127, bq = tid >> 7;
    float acc[32];
    #pragma unroll
    for (int i = 0; i < 32; i++) acc[i] = 0.f;
    for (int jc = 0; jc < 8; jc++) {
        __syncthreads();
        #pragma unroll
        for (int r = 0; r < 16; r++) {
            int e = r * 256 + tid;
            int jl = e >> 6, b = e & 63;
            tile[e] = bf16tof(encJ[(jc * 64 + jl) * (Sn * Bn) + s * Bn + b]);
        }
        __syncthreads();
        for (int jl = 0; jl < 64; jl++) {
            float wv = bf16tof(W2Tb[(jc * 64 + jl) * Un + u]);
            const float4* trow = (const float4*)&tile[jl * 64 + bq * 32];
            #pragma unroll
            for (int i = 0; i < 8; i++) {
                float4 t4 = trow[i];
                acc[i*4+0] += t4.x * wv; acc[i*4+1] += t4.y * wv;
                acc[i*4+2] += t4.z * wv; acc[i*4+3] += t4.w * wv;
            }
        }
    }
    float bb = b2[u];
    #pragma unroll
    for (int i = 0; i < 32; i++)
        w2eb[(((size_t)(bq * 32 + i)) * Sn + s) * Un + u] = bf16rtn(acc[i] + bb);  // w2eb[b][s][u]
}

// ============================ decoder kernels ============================
__global__ __launch_bounds__(256)
void dec_attn_k(const float* __restrict__ hdec, const short* __restrict__ encJ,
                const float* __restrict__ W1T, const float* __restrict__ b1,
                const float* __restrict__ Vv, const float* __restrict__ bV,
                const short* __restrict__ w2eb, const float* __restrict__ oW,
                const float* __restrict__ ob, float* __restrict__ eT,
                float* __restrict__ sumE, float* __restrict__ out, int t)
{
    __shared__ float hs[512];
    __shared__ float w1h[Un];
    __shared__ float Vs[Un];
    __shared__ float red2[256];
    const int tid = threadIdx.x;
    const int b = blockIdx.x >> 2, sc = blockIdx.x & 3;

    if (t == 0) {   // h_att = encoder final h, from encJ at s = Sn-1
        hs[tid]       = bf16tof(encJ[tid * (Sn * Bn) + (Sn - 1) * Bn + b]);
        hs[tid + 256] = bf16tof(encJ[(tid + 256) * (Sn * Bn) + (Sn - 1) * Bn + b]);
    } else {
        hs[tid]       = hdec[tid * Bn + b];
        hs[tid + 256] = hdec[(tid + 256) * Bn + b];
    }
    if (tid < 128) Vs[tid] = Vv[tid];
    __syncthreads();

    if (sc == 0 && t > 0) {                           // out for previous step
        red2[tid] = oW[tid] * hs[tid] + oW[tid + 256] * hs[tid + 256];
        __syncthreads();
        for (int w = 128; w > 0; w >>= 1) { if (tid < w) red2[tid] += red2[tid + w]; __syncthreads(); }
        if (tid == 0) out[b * Tn + (t - 1)] = red2[0] + ob[0];
        __syncthreads();
    }

    {   // w1h[u] = b1[u] + sum_k W1T[k][u] * hs[k]
        const int u = tid & 127, kh = tid >> 7;
        float a = 0.f;
        #pragma unroll 8
        for (int k = 0; k < 256; k++) {
            int kk = kh * 256 + k;
            a += W1T[kk * Un + u] * hs[kk];
        }
        red2[tid] = a;
    }
    __syncthreads();
    if (tid < 128) w1h[tid] = red2[tid] + red2[tid + 128] + b1[tid];
    __syncthreads();

    const int sl = sc * 128 + (tid >> 1), uh = tid & 1;
    const short* r  = w2eb + ((size_t)b * Sn + sl) * Un + uh * 64;
    const float* wp = w1h + uh * 64;
    const float* vp = Vs + uh * 64;
    float s0 = 0.f;
    #pragma unroll
    for (int q = 0; q < 8; q++) {
        bf16x8 v8 = *(const bf16x8*)(r + q * 8);
        #pragma unroll
        for (int e2 = 0; e2 < 8; e2++)
            s0 += vp[q * 8 + e2] * tanh_f(wp[q * 8 + e2] + bf16tof(v8[e2]));
    }
    s0 += __shfl_xor(s0, 1);
    float e = 0.f;
    if (uh == 0) {
        e = __expf(s0 + bV[0]);
        eT[sl * Bn + b] = e;
    }
    __syncthreads();
    red2[tid] = e;
    __syncthreads();
    for (int w = 128; w > 0; w >>= 1) { if (tid < w) red2[tid] += red2[tid + w]; __syncthreads(); }
    if (tid == 0) atomicAdd(&sumE[t * Bn + b], red2[0]);
}

// ctx[j][b] = sum_s e[s][b] * encJ[j][s][b]   (unnormalized; coalesced bf16 reads)
__global__ __launch_bounds__(256)
void dec_ctx_k(const float* __restrict__ eT, const short* __restrict__ encJ,
               float* __restrict__ ctx)
{
    const int tid = threadIdx.x;
    const int j = blockIdx.x;
    const int b = tid & 63, sq = tid >> 6;
    const short* ep = encJ + j * (Sn * Bn) + b;
    float a = 0.f;
    #pragma unroll 8
    for (int s = sq * 128; s < sq * 128 + 128; s++)
        a += eT[s * Bn + b] * bf16tof(ep[s * Bn]);
    __shared__ float red[256];
    red[tid] = a;
    __syncthreads();
    if (sq == 0) ctx[j * Bn + b] = red[b] + red[64 + b] + red[128 + b] + red[192 + b];
}

// decoder LSTM cell (zero init state: only i,g,o gates); 1/sumE folded in.
__global__ __launch_bounds__(256)
void dec_gate_k(const float* __restrict__ ctx, const float* __restrict__ sumE,
                const float* __restrict__ WiT, const float* __restrict__ WgT,
                const float* __restrict__ WoT, const float* __restrict__ dbih,
                const float* __restrict__ dbhh, float* __restrict__ hdec, int t)
{
    const int tid = threadIdx.x;
    const int b = tid & 63, kq = tid >> 6;
    const int j = blockIdx.x;
    float ai = 0.f, ag = 0.f, ao = 0.f;
    #pragma unroll 4
    for (int k = kq * 128; k < kq * 128 + 128; k++) {
        float cv = ctx[k * Bn + b];
        ai += WiT[k * Hn + j] * cv;
        ag += WgT[k * Hn + j] * cv;
        ao += WoT[k * Hn + j] * cv;
    }
    __shared__ float red[3][4][64];
    red[0][kq][b] = ai; red[1][kq][b] = ag; red[2][kq][b] = ao;
    __syncthreads();
    if (kq == 0) {
        float inv = 1.0f / sumE[t * Bn + b];
        float pi = (red[0][0][b] + red[0][1][b] + red[0][2][b] + red[0][3][b]) * inv + dbih[j] + dbhh[j];
        float pg = (red[1][0][b] + red[1][1][b] + red[1][2][b] + red[1][3][b]) * inv + dbih[2*Hn + j] + dbhh[2*Hn + j];
        float po = (red[2][0][b] + red[2][1][b] + red[2][2][b] + red[2][3][b]) * inv + dbih[3*Hn + j] + dbhh[3*Hn + j];
        float cc = sigm(pi) * tanh_f(pg);
        float hh = sigm(po) * tanh_f(cc);
        hdec[j * Bn + b] = hh;
    }
}

// final out step (t = Tn-1)
__global__ __launch_bounds__(64)
void dec_out_k(const float* __restrict__ hdec, const float* __restrict__ oW,
               const float* __restrict__ ob, float* __restrict__ out, int t)
{
    const int b = blockIdx.x;
    const int tid = threadIdx.x;
    float a = 0.f;
    #pragma unroll
    for (int q = 0; q < 8; q++) {
        int j = tid + q * 64;
        a += oW[j] * hdec[j * Bn + b];
    }
    for (int off = 32; off; off >>= 1) a += __shfl_down(a, off, 64);
    if (tid == 0) out[b * Tn + t] = a + ob[0];
}

// ============================ host ============================
extern "C" void kernel_launch(void* const* d_in, const int* in_sizes, int n_in,
                              void* d_out, int out_size, void* d_ws, size_t ws_size,
                              hipStream_t stream) {
    const float* x    = (const float*)d_in[0];
    const float* eWih = (const float*)d_in[1];
    const float* eWhh = (const float*)d_in[2];
    const float* ebih = (const float*)d_in[3];
    const float* ebhh = (const float*)d_in[4];
    const float* aW1  = (const float*)d_in[5];
    const float* ab1  = (const float*)d_in[6];
    const float* aW2  = (const float*)d_in[7];
    const float* ab2  = (const float*)d_in[8];
    const float* aV   = (const float*)d_in[9];
    const float* abV  = (const float*)d_in[10];
    const float* dWih = (const float*)d_in[11];
    // d_in[12] = dec_Whh unused (decoder starts from zero state every step)
    const float* dbih = (const float*)d_in[13];
    const float* dbhh = (const float*)d_in[14];
    const float* oW   = (const float*)d_in[15];
    const float* ob   = (const float*)d_in[16];
    float* out = (float*)d_out;

    char* wsb = (char*)d_ws;
    short* xhi    = (short*)(wsb + 0);          // 4,194,304 B
    short* xlo    = (short*)(wsb + 4194304);    // 4,194,304
    short* whhHi  = (short*)(wsb + 8388608);    // 2,097,152
    short* whhLo  = (short*)(wsb + 10485760);   // 2,097,152
    short* wihHi  = (short*)(wsb + 12582912);   // 262,144
    short* wihLo  = (short*)(wsb + 12845056);   // 262,144
    float* bperm  = (float*)(wsb + 13107200);   // 8,192
    short* W2Tb   = (short*)(wsb + 13115392);   // 131,072
    float* W1T    = (float*)(wsb + 13246464);   // 262,144
    float* WiT    = (float*)(wsb + 13508608);   // 1,048,576
    float* WgT    = (float*)(wsb + 14557184);   // 1,048,576
    float* WoT    = (float*)(wsb + 15605760);   // 1,048,576
    u32*   hPk    = (u32*)  (wsb + 16654336);   // 262,144  [2][64][512] u32
    u32*   flags  = (u32*)  (wsb + 16916480);   // 2,048    [32][16] u32
    short* encJ   = (short*)(wsb + 16918528);   // 33,554,432  [512][512][64] bf16
    short* w2eb   = (short*)(wsb + 50472960);   // 8,388,608   [64][512][128] bf16
    float* eT     = (float*)(wsb + 58861568);   // 131,072
    float* sumE   = (float*)(wsb + 58992640);   // 24,576
    float* ctx    = (float*)(wsb + 59017216);   // 131,072
    float* hdec   = (float*)(wsb + 59148288);   // 131,072

    // ---- setup ----
    k_split_x      <<<8192, 256, 0, stream>>>(x, xhi, xlo);
    k_split_whh    <<<4096, 256, 0, stream>>>(eWhh, whhHi, whhLo);
    k_split_wih    <<<512,  256, 0, stream>>>(eWih, wihHi, wihLo);
    k_bias_perm    <<<8,    256, 0, stream>>>(ebih, ebhh, bperm);
    k_w1t          <<<256,  256, 0, stream>>>(aW1, W1T);
    k_w2t_bf16     <<<256,  256, 0, stream>>>(aW2, W2Tb);
    k_transpose_dec<<<1024, 256, 0, stream>>>(dWih, WiT, WgT, WoT);
    k_zero_state   <<<282,  256, 0, stream>>>(hPk, sumE);

    // ---- encoder: ONE persistent launch, 32 blocks, LDS-staged h ----
    enc_persist3<<<32, 256, 0, stream>>>(xhi, xlo, whhHi, whhLo, wihHi, wihLo,
                                         bperm, hPk, flags, encJ);

    // ---- attention hoist ----
    w2enc_k<<<512, 256, 0, stream>>>(encJ, W2Tb, ab2, w2eb);

    // ---- decoder: 3 kernels per step ----
    for (int t = 0; t < Tn; t++) {
        dec_attn_k<<<256, 256, 0, stream>>>(hdec, encJ, W1T, ab1, aV, abV, w2eb,
                                            oW, ob, eT, sumE, out, t);
        dec_ctx_k <<<512, 256, 0, stream>>>(eT, encJ, ctx);
        dec_gate_k<<<512, 256, 0, stream>>>(ctx, sumE, WiT, WgT, WoT, dbih, dbhh, hdec, t);
    }
    dec_out_k<<<64, 64, 0, stream>>>(hdec, oW, ob, out, Tn - 1);
}

// Round 6
// 9844.021 us; speedup vs baseline: 1.2127x; 1.2127x over previous
//
#include <hip/hip_runtime.h>

#define Bn 64
#define Sn 512
#define Fn 64
#define Hn 512
#define Un 128
#define Tn 96

typedef __attribute__((ext_vector_type(8))) short bf16x8;
typedef __attribute__((ext_vector_type(4))) float f32x4;
typedef unsigned int u32;

#define MFMA16(a, b, c) __builtin_amdgcn_mfma_f32_16x16x32_bf16(a, b, c, 0, 0, 0)

__device__ __forceinline__ float sigm(float x) { return 1.0f / (1.0f + __expf(-x)); }
__device__ __forceinline__ float tanh_f(float x) {
    x = fminf(fmaxf(x, -15.0f), 15.0f);
    float e = __expf(2.0f * x);
    return (e - 1.0f) / (e + 1.0f);
}
__device__ __forceinline__ short bf16rtn(float f) {
    unsigned u = __float_as_uint(f);
    unsigned r = (u + 0x7FFFu + ((u >> 16) & 1u)) >> 16;
    return (short)r;
}
__device__ __forceinline__ float bf16tof(short s) {
    return __uint_as_float(((unsigned)(unsigned short)s) << 16);
}

// ============================ setup kernels ============================
__global__ __launch_bounds__(256) void k_split_x(const float* __restrict__ x,
                                                 short* __restrict__ xhi, short* __restrict__ xlo) {
    int t = blockIdx.x * 256 + threadIdx.x;          // 2,097,152 = B*S*F
    int f = t & 63, s = (t >> 6) & 511, b = t >> 15;
    float v = x[t];
    short hi = bf16rtn(v);
    short lo = bf16rtn(v - bf16tof(hi));
    int o = (s * Bn + b) * Fn + f;                   // x[s][b][f]
    xhi[o] = hi; xlo[o] = lo;
}
__global__ __launch_bounds__(256) void k_split_whh(const float* __restrict__ w,
                                                   short* __restrict__ whi, short* __restrict__ wlo) {
    int t = blockIdx.x * 256 + threadIdx.x;          // 1,048,576
    int k = t & 511, r = t >> 9;                     // r = g*512+j
    int g = r >> 9, j = r & 511;
    float v = w[t];
    short hi = bf16rtn(v);
    short lo = bf16rtn(v - bf16tof(hi));
    int o = (j * 4 + g) * 512 + k;                   // row' = j*4+g
    whi[o] = hi; wlo[o] = lo;
}
__global__ __launch_bounds__(256) void k_split_wih(const float* __restrict__ w,
                                                   short* __restrict__ whi, short* __restrict__ wlo) {
    int t = blockIdx.x * 256 + threadIdx.x;          // 131,072
    int k = t & 63, r = t >> 6;
    int g = r >> 9, j = r & 511;
    float v = w[t];
    short hi = bf16rtn(v);
    short lo = bf16rtn(v - bf16tof(hi));
    int o = (j * 4 + g) * 64 + k;
    whi[o] = hi; wlo[o] = lo;
}
__global__ __launch_bounds__(256) void k_bias_perm(const float* __restrict__ bih,
                                                   const float* __restrict__ bhh,
                                                   float* __restrict__ bperm) {
    int t = blockIdx.x * 256 + threadIdx.x;          // 2048
    int g = t >> 9, j = t & 511;
    bperm[j * 4 + g] = bih[t] + bhh[t];
}
__global__ __launch_bounds__(256) void k_w1t(const float* __restrict__ W1, float* __restrict__ W1T) {
    int t = blockIdx.x * 256 + threadIdx.x;          // 65,536 = U*H
    int u = t >> 9, k = t & 511;
    W1T[k * Un + u] = W1[t];
}
__global__ __launch_bounds__(256) void k_w2t_bf16(const float* __restrict__ W2, short* __restrict__ W2Tb) {
    int t = blockIdx.x * 256 + threadIdx.x;          // 65,536 = U*H
    int u = t >> 9, j = t & 511;
    W2Tb[j * Un + u] = bf16rtn(W2[t]);
}
__global__ __launch_bounds__(256) void k_transpose_dec(const float* __restrict__ dW, float* __restrict__ WiT,
                                                       float* __restrict__ WgT, float* __restrict__ WoT) {
    int t = blockIdx.x * 256 + threadIdx.x;          // 262,144 ; dec_Wih rows length 513
    int j = t & 511, j2 = t >> 9;
    WiT[t] = dW[(j)        * 513 + j2];              // WiT[k=j2][j]
    WgT[t] = dW[(1024 + j) * 513 + j2];
    WoT[t] = dW[(1536 + j) * 513 + j2];
}
// zero: hHi+hLo ping-pong + cstG (contiguous 98,304 f32) and sumE (6,144 f32)
__global__ __launch_bounds__(256) void k_zero_state(float* __restrict__ hz, float* __restrict__ se) {
    int t = blockIdx.x * 256 + threadIdx.x;          // 104,448 = 408*256
    if (t < 98304) hz[t] = 0.0f;
    else se[t - 98304] = 0.0f;
}

// ============================ encoder: one launch per step (v2) ============================
// Grid 128: block jt owns output rows jt*16..+16 (rows = j*4+g), ALL 64 batch
// cols. Wave wv owns cols wv*16..+16 with FULL K=512: no LDS reduction, no
// __syncthreads, all-wave parallel epilogue. bf16x3 (AhiBh+AhiBl+AloBh).
// C/D layout (verified): col=lane&15, row=(lane>>4)*4+reg -> lane's 4 acc regs
// are gates i,f,g,o of j = jt*4+(lane>>4), batch col = wv*16+(lane&15).
// A-tile read once per block (no jt duplication): 4 MB/step L2-side total.
__global__ __launch_bounds__(256)
void enc_step2(const short* __restrict__ xhi, const short* __restrict__ xlo,
               const short* __restrict__ whhHi, const short* __restrict__ whhLo,
               const short* __restrict__ wihHi, const short* __restrict__ wihLo,
               const float* __restrict__ bperm,
               const short* __restrict__ hHiP, const short* __restrict__ hLoP,
               short* __restrict__ hHiN, short* __restrict__ hLoN,
               float* __restrict__ cstG, short* __restrict__ encJ, int t)
{
    const int jt = blockIdx.x;
    const int tid = threadIdx.x;
    const int wv = tid >> 6, l = tid & 63;
    const int lr = l & 15, lk = l >> 4;
    const int row  = jt * 16 + lr;                   // A-frag row (gate-row)
    const int bcol = wv * 16 + lr;                   // B-frag col (batch)

    f32x4 acc = {0.f, 0.f, 0.f, 0.f};
    // x part first (issue early)
    {
        bf16x8 XB[2][2];
        #pragma unroll
        for (int cw = 0; cw < 2; cw++) {
            int k0 = cw * 32 + lk * 8;
            XB[cw][0] = *(const bf16x8*)(xhi + ((size_t)t * 64 + bcol) * 64 + k0);
            XB[cw][1] = *(const bf16x8*)(xlo + ((size_t)t * 64 + bcol) * 64 + k0);
        }
        #pragma unroll
        for (int cw = 0; cw < 2; cw++) {
            int k0 = cw * 32 + lk * 8;
            bf16x8 Ah = *(const bf16x8*)(wihHi + (size_t)row * 64 + k0);
            bf16x8 Al = *(const bf16x8*)(wihLo + (size_t)row * 64 + k0);
            acc = MFMA16(Ah, XB[cw][0], acc);
            acc = MFMA16(Ah, XB[cw][1], acc);
            acc = MFMA16(Al, XB[cw][0], acc);
        }
    }
    // recurrent part: K=512 in 16 chunks of 32
    #pragma unroll 4
    for (int c = 0; c < 16; c++) {
        int k0 = c * 32 + lk * 8;
        bf16x8 Ah = *(const bf16x8*)(whhHi + (size_t)row * 512 + k0);
        bf16x8 Al = *(const bf16x8*)(whhLo + (size_t)row * 512 + k0);
        bf16x8 Bh = *(const bf16x8*)(hHiP + (size_t)bcol * 512 + k0);
        bf16x8 Bl = *(const bf16x8*)(hLoP + (size_t)bcol * 512 + k0);
        acc = MFMA16(Ah, Bh, acc);
        acc = MFMA16(Ah, Bl, acc);
        acc = MFMA16(Al, Bh, acc);
    }
    // epilogue: every lane owns (j = jt*4+lk, b = bcol)
    const int jloc = jt * 4 + lk;
    const f32x4 bias = *(const f32x4*)(bperm + jt * 16 + lk * 4);
    float pi = acc[0] + bias[0];
    float pf = acc[1] + bias[1];
    float pg = acc[2] + bias[2];
    float po = acc[3] + bias[3];
    float ig = sigm(pi), fg = sigm(pf), gg = tanh_f(pg), og = sigm(po);
    float cn = fg * cstG[jloc * Bn + bcol] + ig * gg;
    float hv = og * tanh_f(cn);
    cstG[jloc * Bn + bcol] = cn;
    short hi16 = bf16rtn(hv);
    short lo16 = bf16rtn(hv - bf16tof(hi16));
    hHiN[bcol * 512 + jloc] = hi16;
    hLoN[bcol * 512 + jloc] = lo16;
    encJ[(size_t)jloc * (Sn * Bn) + t * Bn + bcol] = hi16;   // encJ[j][s][b] bf16
}

// ============================ w2_enc GEMM (bf16 in/out) ============================
__global__ __launch_bounds__(256)
void w2enc_k(const short* __restrict__ encJ, const short* __restrict__ W2Tb,
             const float* __restrict__ b2, short* __restrict__ w2eb)
{
    __shared__ float tile[64 * 64];
    const int s = blockIdx.x;
    const int tid = threadIdx.x;
    const int u = tid & 127, bq = tid >> 7;
    float acc[32];
    #pragma unroll
    for (int i = 0; i < 32; i++) acc[i] = 0.f;
    for (int jc = 0; jc < 8; jc++) {
        __syncthreads();
        #pragma unroll
        for (int r = 0; r < 16; r++) {
            int e = r * 256 + tid;
            int jl = e >> 6, b = e & 63;
            tile[e] = bf16tof(encJ[(jc * 64 + jl) * (Sn * Bn) + s * Bn + b]);
        }
        __syncthreads();
        for (int jl = 0; jl < 64; jl++) {
            float wv = bf16tof(W2Tb[(jc * 64 + jl) * Un + u]);
            const float4* trow = (const float4*)&tile[jl * 64 + bq * 32];
            #pragma unroll
            for (int i = 0; i < 8; i++) {
                float4 t4 = trow[i];
                acc[i*4+0] += t4.x * wv; acc[i*4+1] += t4.y * wv;
                acc[i*4+2] += t4.z * wv; acc[i*4+3] += t4.w * wv;
            }
        }
    }
    float bb = b2[u];
    #pragma unroll
    for (int i = 0; i < 32; i++)
        w2eb[(((size_t)(bq * 32 + i)) * Sn + s) * Un + u] = bf16rtn(acc[i] + bb);  // w2eb[b][s][u]
}

// ============================ decoder kernels ============================
// block (b = blk>>2, sc = blk&3). Max-free softmax (|score| <= sum|V| ~ 6):
// e = exp(score); partial sums atomically into sumE. sc==0 also emits out[t-1].
__global__ __launch_bounds__(256)
void dec_attn_k(const float* __restrict__ hdec, const short* __restrict__ encJ,
                const float* __restrict__ W1T, const float* __restrict__ b1,
                const float* __restrict__ Vv, const float* __restrict__ bV,
                const short* __restrict__ w2eb, const float* __restrict__ oW,
                const float* __restrict__ ob, float* __restrict__ eT,
                float* __restrict__ sumE, float* __restrict__ out, int t)
{
    __shared__ float hs[512];
    __shared__ float w1h[Un];
    __shared__ float Vs[Un];
    __shared__ float red2[256];
    const int tid = threadIdx.x;
    const int b = blockIdx.x >> 2, sc = blockIdx.x & 3;

    if (t == 0) {   // h_att = encoder final h, from encJ at s = Sn-1
        hs[tid]       = bf16tof(encJ[tid * (Sn * Bn) + (Sn - 1) * Bn + b]);
        hs[tid + 256] = bf16tof(encJ[(tid + 256) * (Sn * Bn) + (Sn - 1) * Bn + b]);
    } else {
        hs[tid]       = hdec[tid * Bn + b];
        hs[tid + 256] = hdec[(tid + 256) * Bn + b];
    }
    if (tid < 128) Vs[tid] = Vv[tid];
    __syncthreads();

    if (sc == 0 && t > 0) {                           // out for previous step
        red2[tid] = oW[tid] * hs[tid] + oW[tid + 256] * hs[tid + 256];
        __syncthreads();
        for (int w = 128; w > 0; w >>= 1) { if (tid < w) red2[tid] += red2[tid + w]; __syncthreads(); }
        if (tid == 0) out[b * Tn + (t - 1)] = red2[0] + ob[0];
        __syncthreads();
    }

    {   // w1h[u] = b1[u] + sum_k W1T[k][u] * hs[k]
        const int u = tid & 127, kh = tid >> 7;
        float a = 0.f;
        #pragma unroll 8
        for (int k = 0; k < 256; k++) {
            int kk = kh * 256 + k;
            a += W1T[kk * Un + u] * hs[kk];
        }
        red2[tid] = a;
    }
    __syncthreads();
    if (tid < 128) w1h[tid] = red2[tid] + red2[tid + 128] + b1[tid];
    __syncthreads();

    const int sl = sc * 128 + (tid >> 1), uh = tid & 1;
    const short* r  = w2eb + ((size_t)b * Sn + sl) * Un + uh * 64;
    const float* wp = w1h + uh * 64;
    const float* vp = Vs + uh * 64;
    float s0 = 0.f;
    #pragma unroll
    for (int q = 0; q < 8; q++) {
        bf16x8 v8 = *(const bf16x8*)(r + q * 8);
        #pragma unroll
        for (int e2 = 0; e2 < 8; e2++)
            s0 += vp[q * 8 + e2] * tanh_f(wp[q * 8 + e2] + bf16tof(v8[e2]));
    }
    s0 += __shfl_xor(s0, 1);
    float e = 0.f;
    if (uh == 0) {
        e = __expf(s0 + bV[0]);
        eT[sl * Bn + b] = e;
    }
    __syncthreads();
    red2[tid] = e;
    __syncthreads();
    for (int w = 128; w > 0; w >>= 1) { if (tid < w) red2[tid] += red2[tid + w]; __syncthreads(); }
    if (tid == 0) atomicAdd(&sumE[t * Bn + b], red2[0]);
}

// ctx[j][b] = sum_s e[s][b] * encJ[j][s][b]   (unnormalized; coalesced bf16 reads)
__global__ __launch_bounds__(256)
void dec_ctx_k(const float* __restrict__ eT, const short* __restrict__ encJ,
               float* __restrict__ ctx)
{
    const int tid = threadIdx.x;
    const int j = blockIdx.x;
    const int b = tid & 63, sq = tid >> 6;
    const short* ep = encJ + j * (Sn * Bn) + b;
    float a = 0.f;
    #pragma unroll 8
    for (int s = sq * 128; s < sq * 128 + 128; s++)
        a += eT[s * Bn + b] * bf16tof(ep[s * Bn]);
    __shared__ float red[256];
    red[tid] = a;
    __syncthreads();
    if (sq == 0) ctx[j * Bn + b] = red[b] + red[64 + b] + red[128 + b] + red[192 + b];
}

// decoder LSTM cell (zero init state: only i,g,o gates); 1/sumE folded in.
__global__ __launch_bounds__(256)
void dec_gate_k(const float* __restrict__ ctx, const float* __restrict__ sumE,
                const float* __restrict__ WiT, const float* __restrict__ WgT,
                const float* __restrict__ WoT, const float* __restrict__ dbih,
                const float* __restrict__ dbhh, float* __restrict__ hdec, int t)
{
    const int tid = threadIdx.x;
    const int b = tid & 63, kq = tid >> 6;
    const int j = blockIdx.x;
    float ai = 0.f, ag = 0.f, ao = 0.f;
    #pragma unroll 4
    for (int k = kq * 128; k < kq * 128 + 128; k++) {
        float cv = ctx[k * Bn + b];
        ai += WiT[k * Hn + j] * cv;
        ag += WgT[k * Hn + j] * cv;
        ao += WoT[k * Hn + j] * cv;
    }
    __shared__ float red[3][4][64];
    red[0][kq][b] = ai; red[1][kq][b] = ag; red[2][kq][b] = ao;
    __syncthreads();
    if (kq == 0) {
        float inv = 1.0f / sumE[t * Bn + b];
        float pi = (red[0][0][b] + red[0][1][b] + red[0][2][b] + red[0][3][b]) * inv + dbih[j] + dbhh[j];
        float pg = (red[1][0][b] + red[1][1][b] + red[1][2][b] + red[1][3][b]) * inv + dbih[2*Hn + j] + dbhh[2*Hn + j];
        float po = (red[2][0][b] + red[2][1][b] + red[2][2][b] + red[2][3][b]) * inv + dbih[3*Hn + j] + dbhh[3*Hn + j];
        float cc = sigm(pi) * tanh_f(pg);
        float hh = sigm(po) * tanh_f(cc);
        hdec[j * Bn + b] = hh;
    }
}

// final out step (t = Tn-1)
__global__ __launch_bounds__(64)
void dec_out_k(const float* __restrict__ hdec, const float* __restrict__ oW,
               const float* __restrict__ ob, float* __restrict__ out, int t)
{
    const int b = blockIdx.x;
    const int tid = threadIdx.x;
    float a = 0.f;
    #pragma unroll
    for (int q = 0; q < 8; q++) {
        int j = tid + q * 64;
        a += oW[j] * hdec[j * Bn + b];
    }
    for (int off = 32; off; off >>= 1) a += __shfl_down(a, off, 64);
    if (tid == 0) out[b * Tn + t] = a + ob[0];
}

// ============================ host ============================
extern "C" void kernel_launch(void* const* d_in, const int* in_sizes, int n_in,
                              void* d_out, int out_size, void* d_ws, size_t ws_size,
                              hipStream_t stream) {
    const float* x    = (const float*)d_in[0];
    const float* eWih = (const float*)d_in[1];
    const float* eWhh = (const float*)d_in[2];
    const float* ebih = (const float*)d_in[3];
    const float* ebhh = (const float*)d_in[4];
    const float* aW1  = (const float*)d_in[5];
    const float* ab1  = (const float*)d_in[6];
    const float* aW2  = (const float*)d_in[7];
    const float* ab2  = (const float*)d_in[8];
    const float* aV   = (const float*)d_in[9];
    const float* abV  = (const float*)d_in[10];
    const float* dWih = (const float*)d_in[11];
    // d_in[12] = dec_Whh unused (decoder starts from zero state every step)
    const float* dbih = (const float*)d_in[13];
    const float* dbhh = (const float*)d_in[14];
    const float* oW   = (const float*)d_in[15];
    const float* ob   = (const float*)d_in[16];
    float* out = (float*)d_out;

    char* wsb = (char*)d_ws;
    short* xhi    = (short*)(wsb + 0);          // 4,194,304 B
    short* xlo    = (short*)(wsb + 4194304);    // 4,194,304
    short* whhHi  = (short*)(wsb + 8388608);    // 2,097,152
    short* whhLo  = (short*)(wsb + 10485760);   // 2,097,152
    short* wihHi  = (short*)(wsb + 12582912);   // 262,144
    short* wihLo  = (short*)(wsb + 12845056);   // 262,144
    float* bperm  = (float*)(wsb + 13107200);   // 8,192
    short* W2Tb   = (short*)(wsb + 13115392);   // 131,072
    float* W1T    = (float*)(wsb + 13246464);   // 262,144
    float* WiT    = (float*)(wsb + 13508608);   // 1,048,576
    float* WgT    = (float*)(wsb + 14557184);   // 1,048,576
    float* WoT    = (float*)(wsb + 15605760);   // 1,048,576
    short* hHi    = (short*)(wsb + 16654336);   // 131,072  [2][32768]
    short* hLo    = (short*)(wsb + 16785408);   // 131,072  [2][32768]
    float* cstG   = (float*)(wsb + 16916480);   // 131,072
    short* encJ   = (short*)(wsb + 17047552);   // 33,554,432  [512][512][64] bf16
    short* w2eb   = (short*)(wsb + 50601984);   // 8,388,608   [64][512][128] bf16
    float* eT     = (float*)(wsb + 58990592);   // 131,072
    float* sumE   = (float*)(wsb + 59121664);   // 24,576
    float* ctx    = (float*)(wsb + 59146240);   // 131,072
    float* hdec   = (float*)(wsb + 59277312);   // 131,072

    // ---- setup ----
    k_split_x      <<<8192, 256, 0, stream>>>(x, xhi, xlo);
    k_split_whh    <<<4096, 256, 0, stream>>>(eWhh, whhHi, whhLo);
    k_split_wih    <<<512,  256, 0, stream>>>(eWih, wihHi, wihLo);
    k_bias_perm    <<<8,    256, 0, stream>>>(ebih, ebhh, bperm);
    k_w1t          <<<256,  256, 0, stream>>>(aW1, W1T);
    k_w2t_bf16     <<<256,  256, 0, stream>>>(aW2, W2Tb);
    k_transpose_dec<<<1024, 256, 0, stream>>>(dWih, WiT, WgT, WoT);
    k_zero_state   <<<408,  256, 0, stream>>>((float*)hHi, sumE);

    // ---- encoder: 512 per-step launches (kernel boundary = grid barrier) ----
    for (int t = 0; t < Sn; t++) {
        const int pr = t & 1, pw = 1 - pr;
        enc_step2<<<128, 256, 0, stream>>>(xhi, xlo, whhHi, whhLo, wihHi, wihLo,
                                           bperm,
                                           hHi + pr * 32768, hLo + pr * 32768,
                                           hHi + pw * 32768, hLo + pw * 32768,
                                           cstG, encJ, t);
    }

    // ---- attention hoist ----
    w2enc_k<<<512, 256, 0, stream>>>(encJ, W2Tb, ab2, w2eb);

    // ---- decoder: 3 kernels per step ----
    for (int t = 0; t < Tn; t++) {
        dec_attn_k<<<256, 256, 0, stream>>>(hdec, encJ, W1T, ab1, aV, abV, w2eb,
                                            oW, ob, eT, sumE, out, t);
        dec_ctx_k <<<512, 256, 0, stream>>>(eT, encJ, ctx);
        dec_gate_k<<<512, 256, 0, stream>>>(ctx, sumE, WiT, WgT, WoT, dbih, dbhh, hdec, t);
    }
    dec_out_k<<<64, 64, 0, stream>>>(hdec, oW, ob, out, Tn - 1);
}

// Round 7
// 7502.721 us; speedup vs baseline: 1.5911x; 1.3121x over previous
//
#include <hip/hip_runtime.h>

#define Bn 64
#define Sn 512
#define Fn 64
#define Hn 512
#define Un 128
#define Tn 96

typedef __attribute__((ext_vector_type(8))) short bf16x8;
typedef __attribute__((ext_vector_type(4))) float f32x4;
typedef unsigned int u32;

#define MFMA16(a, b, c) __builtin_amdgcn_mfma_f32_16x16x32_bf16(a, b, c, 0, 0, 0)

__device__ __forceinline__ float sigm(float x) { return 1.0f / (1.0f + __expf(-x)); }
__device__ __forceinline__ float tanh_f(float x) {
    x = fminf(fmaxf(x, -15.0f), 15.0f);
    float e = __expf(2.0f * x);
    return (e - 1.0f) / (e + 1.0f);
}
__device__ __forceinline__ short bf16rtn(float f) {
    unsigned u = __float_as_uint(f);
    unsigned r = (u + 0x7FFFu + ((u >> 16) & 1u)) >> 16;
    return (short)r;
}
__device__ __forceinline__ float bf16tof(short s) {
    return __uint_as_float(((unsigned)(unsigned short)s) << 16);
}

// ============================ setup kernels ============================
__global__ __launch_bounds__(256) void k_split_x(const float* __restrict__ x,
                                                 short* __restrict__ xhi, short* __restrict__ xlo) {
    int t = blockIdx.x * 256 + threadIdx.x;          // 2,097,152 = B*S*F
    int f = t & 63, s = (t >> 6) & 511, b = t >> 15;
    float v = x[t];
    short hi = bf16rtn(v);
    short lo = bf16rtn(v - bf16tof(hi));
    int o = (s * Bn + b) * Fn + f;                   // x[s][b][f]
    xhi[o] = hi; xlo[o] = lo;
}
__global__ __launch_bounds__(256) void k_split_whh(const float* __restrict__ w,
                                                   short* __restrict__ whi, short* __restrict__ wlo) {
    int t = blockIdx.x * 256 + threadIdx.x;          // 1,048,576
    int k = t & 511, r = t >> 9;                     // r = g*512+j
    int g = r >> 9, j = r & 511;
    float v = w[t];
    short hi = bf16rtn(v);
    short lo = bf16rtn(v - bf16tof(hi));
    int o = (j * 4 + g) * 512 + k;                   // row' = j*4+g
    whi[o] = hi; wlo[o] = lo;
}
__global__ __launch_bounds__(256) void k_split_wih(const float* __restrict__ w,
                                                   short* __restrict__ whi, short* __restrict__ wlo) {
    int t = blockIdx.x * 256 + threadIdx.x;          // 131,072
    int k = t & 63, r = t >> 6;
    int g = r >> 9, j = r & 511;
    float v = w[t];
    short hi = bf16rtn(v);
    short lo = bf16rtn(v - bf16tof(hi));
    int o = (j * 4 + g) * 64 + k;
    whi[o] = hi; wlo[o] = lo;
}
__global__ __launch_bounds__(256) void k_bias_perm(const float* __restrict__ bih,
                                                   const float* __restrict__ bhh,
                                                   float* __restrict__ bperm) {
    int t = blockIdx.x * 256 + threadIdx.x;          // 2048
    int g = t >> 9, j = t & 511;
    bperm[j * 4 + g] = bih[t] + bhh[t];
}
__global__ __launch_bounds__(256) void k_w1t(const float* __restrict__ W1, float* __restrict__ W1T) {
    int t = blockIdx.x * 256 + threadIdx.x;          // 65,536 = U*H
    int u = t >> 9, k = t & 511;
    W1T[k * Un + u] = W1[t];
}
__global__ __launch_bounds__(256) void k_w2t_bf16(const float* __restrict__ W2, short* __restrict__ W2Tb) {
    int t = blockIdx.x * 256 + threadIdx.x;          // 65,536 = U*H
    int u = t >> 9, j = t & 511;
    W2Tb[j * Un + u] = bf16rtn(W2[t]);
}
__global__ __launch_bounds__(256) void k_transpose_dec(const float* __restrict__ dW, float* __restrict__ WiT,
                                                       float* __restrict__ WgT, float* __restrict__ WoT) {
    int t = blockIdx.x * 256 + threadIdx.x;          // 262,144 ; dec_Wih rows length 513
    int j = t & 511, j2 = t >> 9;
    WiT[t] = dW[(j)        * 513 + j2];              // WiT[k=j2][j]
    WgT[t] = dW[(1024 + j) * 513 + j2];
    WoT[t] = dW[(1536 + j) * 513 + j2];
}
// zero: hHi+hLo ping-pong + cstG (contiguous 98,304 f32) and sumE (6,144 f32)
__global__ __launch_bounds__(256) void k_zero_state(float* __restrict__ hz, float* __restrict__ se) {
    int t = blockIdx.x * 256 + threadIdx.x;          // 104,448 = 408*256
    if (t < 98304) hz[t] = 0.0f;
    else se[t - 98304] = 0.0f;
}

// ============================ encoder: one launch per step (v3) ============================
// Grid 256 x 512 threads (8 waves). Block (mt = blk>>1, nt = blk&1): output
// rows mt*16..+16 (rows = j*4+g), batch cols nt*32..+32. Wave (nw = wv&1,
// kw = wv>>2? no: kw = wv>>1): nw = col-half (16 cols), kw = K-quarter (128).
// Traffic/step: A 8.4 MB (2x dup) + h 16.4 MB + x/wih ~3 MB = ~28 MB (vs r3 36).
// Occupancy: 256 blocks x 8 waves = 8 waves/CU (= r3). bf16x3 precision.
// C/D layout (verified): col=lane&15, row=(lane>>4)*4+reg -> lane's 4 acc regs
// are gates i,f,g,o of j = mt*4+(lane>>4), batch col = nt*32+nw*16+(lane&15).
__global__ __launch_bounds__(512)
void enc_step3(const short* __restrict__ xhi, const short* __restrict__ xlo,
               const short* __restrict__ whhHi, const short* __restrict__ whhLo,
               const short* __restrict__ wihHi, const short* __restrict__ wihLo,
               const float* __restrict__ bperm,
               const short* __restrict__ hHiP, const short* __restrict__ hLoP,
               short* __restrict__ hHiN, short* __restrict__ hLoN,
               float* __restrict__ cstG, short* __restrict__ encJ, int t)
{
    const int mt = blockIdx.x >> 1, nt = blockIdx.x & 1;
    const int tid = threadIdx.x;
    const int wv = tid >> 6, l = tid & 63;
    const int nw = wv & 1, kw = wv >> 1;
    const int lr = l & 15, lk = l >> 4;
    const int row  = mt * 16 + lr;                   // A-frag row (gate-row)
    const int bcol = nt * 32 + nw * 16 + lr;         // B-frag col (batch)

    f32x4 acc = {0.f, 0.f, 0.f, 0.f};
    // x part on kw<2 (K=64 split 32/32), issued first
    if (kw < 2) {
        int k0 = kw * 32 + lk * 8;
        bf16x8 XBh = *(const bf16x8*)(xhi + ((size_t)t * 64 + bcol) * 64 + k0);
        bf16x8 XBl = *(const bf16x8*)(xlo + ((size_t)t * 64 + bcol) * 64 + k0);
        bf16x8 Ah  = *(const bf16x8*)(wihHi + (size_t)row * 64 + k0);
        bf16x8 Al  = *(const bf16x8*)(wihLo + (size_t)row * 64 + k0);
        acc = MFMA16(Ah, XBh, acc);
        acc = MFMA16(Ah, XBl, acc);
        acc = MFMA16(Al, XBh, acc);
    }
    // recurrent part: this wave's K-quarter (128) in 4 chunks of 32
    #pragma unroll
    for (int c = 0; c < 4; c++) {
        int k0 = kw * 128 + c * 32 + lk * 8;
        bf16x8 Ah = *(const bf16x8*)(whhHi + (size_t)row * 512 + k0);
        bf16x8 Al = *(const bf16x8*)(whhLo + (size_t)row * 512 + k0);
        bf16x8 Bh = *(const bf16x8*)(hHiP + (size_t)bcol * 512 + k0);
        bf16x8 Bl = *(const bf16x8*)(hLoP + (size_t)bcol * 512 + k0);
        acc = MFMA16(Ah, Bh, acc);
        acc = MFMA16(Ah, Bl, acc);
        acc = MFMA16(Al, Bh, acc);
    }
    // K-reduction across kw (4 partials) via LDS
    __shared__ float red[3][2][64][4];
    if (kw) *(f32x4*)(&red[kw - 1][nw][l][0]) = acc;
    __syncthreads();
    if (kw == 0) {
        f32x4 r0 = *(const f32x4*)(&red[0][nw][l][0]);
        f32x4 r1 = *(const f32x4*)(&red[1][nw][l][0]);
        f32x4 r2 = *(const f32x4*)(&red[2][nw][l][0]);
        const int jloc = mt * 4 + lk;
        const f32x4 bias = *(const f32x4*)(bperm + mt * 16 + lk * 4);
        float pi = acc[0] + r0[0] + r1[0] + r2[0] + bias[0];
        float pf = acc[1] + r0[1] + r1[1] + r2[1] + bias[1];
        float pg = acc[2] + r0[2] + r1[2] + r2[2] + bias[2];
        float po = acc[3] + r0[3] + r1[3] + r2[3] + bias[3];
        float ig = sigm(pi), fg = sigm(pf), gg = tanh_f(pg), og = sigm(po);
        float cn = fg * cstG[jloc * Bn + bcol] + ig * gg;
        float hv = og * tanh_f(cn);
        cstG[jloc * Bn + bcol] = cn;
        short hi16 = bf16rtn(hv);
        short lo16 = bf16rtn(hv - bf16tof(hi16));
        hHiN[bcol * 512 + jloc] = hi16;
        hLoN[bcol * 512 + jloc] = lo16;
        encJ[(size_t)jloc * (Sn * Bn) + t * Bn + bcol] = hi16;   // encJ[j][s][b] bf16
    }
}

// ============================ w2_enc GEMM (bf16 in/out) ============================
__global__ __launch_bounds__(256)
void w2enc_k(const short* __restrict__ encJ, const short* __restrict__ W2Tb,
             const float* __restrict__ b2, short* __restrict__ w2eb)
{
    __shared__ float tile[64 * 64];
    const int s = blockIdx.x;
    const int tid = threadIdx.x;
    const int u = tid & 127, bq = tid >> 7;
    float acc[32];
    #pragma unroll
    for (int i = 0; i < 32; i++) acc[i] = 0.f;
    for (int jc = 0; jc < 8; jc++) {
        __syncthreads();
        #pragma unroll
        for (int r = 0; r < 16; r++) {
            int e = r * 256 + tid;
            int jl = e >> 6, b = e & 63;
            tile[e] = bf16tof(encJ[(jc * 64 + jl) * (Sn * Bn) + s * Bn + b]);
        }
        __syncthreads();
        for (int jl = 0; jl < 64; jl++) {
            float wv = bf16tof(W2Tb[(jc * 64 + jl) * Un + u]);
            const float4* trow = (const float4*)&tile[jl * 64 + bq * 32];
            #pragma unroll
            for (int i = 0; i < 8; i++) {
                float4 t4 = trow[i];
                acc[i*4+0] += t4.x * wv; acc[i*4+1] += t4.y * wv;
                acc[i*4+2] += t4.z * wv; acc[i*4+3] += t4.w * wv;
            }
        }
    }
    float bb = b2[u];
    #pragma unroll
    for (int i = 0; i < 32; i++)
        w2eb[(((size_t)(bq * 32 + i)) * Sn + s) * Un + u] = bf16rtn(acc[i] + bb);  // w2eb[b][s][u]
}

// ============================ decoder kernels ============================
// block (b = blk>>2, sc = blk&3). Max-free softmax (|score| <= sum|V| ~ 6):
// e = exp(score); partial sums atomically into sumE. sc==0 also emits out[t-1].
__global__ __launch_bounds__(256)
void dec_attn_k(const float* __restrict__ hdec, const short* __restrict__ encJ,
                const float* __restrict__ W1T, const float* __restrict__ b1,
                const float* __restrict__ Vv, const float* __restrict__ bV,
                const short* __restrict__ w2eb, const float* __restrict__ oW,
                const float* __restrict__ ob, float* __restrict__ eT,
                float* __restrict__ sumE, float* __restrict__ out, int t)
{
    __shared__ float hs[512];
    __shared__ float w1h[Un];
    __shared__ float Vs[Un];
    __shared__ float red2[256];
    const int tid = threadIdx.x;
    const int b = blockIdx.x >> 2, sc = blockIdx.x & 3;

    if (t == 0) {   // h_att = encoder final h, from encJ at s = Sn-1
        hs[tid]       = bf16tof(encJ[tid * (Sn * Bn) + (Sn - 1) * Bn + b]);
        hs[tid + 256] = bf16tof(encJ[(tid + 256) * (Sn * Bn) + (Sn - 1) * Bn + b]);
    } else {
        hs[tid]       = hdec[tid * Bn + b];
        hs[tid + 256] = hdec[(tid + 256) * Bn + b];
    }
    if (tid < 128) Vs[tid] = Vv[tid];
    __syncthreads();

    if (sc == 0 && t > 0) {                           // out for previous step
        red2[tid] = oW[tid] * hs[tid] + oW[tid + 256] * hs[tid + 256];
        __syncthreads();
        for (int w = 128; w > 0; w >>= 1) { if (tid < w) red2[tid] += red2[tid + w]; __syncthreads(); }
        if (tid == 0) out[b * Tn + (t - 1)] = red2[0] + ob[0];
        __syncthreads();
    }

    {   // w1h[u] = b1[u] + sum_k W1T[k][u] * hs[k]
        const int u = tid & 127, kh = tid >> 7;
        float a = 0.f;
        #pragma unroll 8
        for (int k = 0; k < 256; k++) {
            int kk = kh * 256 + k;
            a += W1T[kk * Un + u] * hs[kk];
        }
        red2[tid] = a;
    }
    __syncthreads();
    if (tid < 128) w1h[tid] = red2[tid] + red2[tid + 128] + b1[tid];
    __syncthreads();

    const int sl = sc * 128 + (tid >> 1), uh = tid & 1;
    const short* r  = w2eb + ((size_t)b * Sn + sl) * Un + uh * 64;
    const float* wp = w1h + uh * 64;
    const float* vp = Vs + uh * 64;
    float s0 = 0.f;
    #pragma unroll
    for (int q = 0; q < 8; q++) {
        bf16x8 v8 = *(const bf16x8*)(r + q * 8);
        #pragma unroll
        for (int e2 = 0; e2 < 8; e2++)
            s0 += vp[q * 8 + e2] * tanh_f(wp[q * 8 + e2] + bf16tof(v8[e2]));
    }
    s0 += __shfl_xor(s0, 1);
    float e = 0.f;
    if (uh == 0) {
        e = __expf(s0 + bV[0]);
        eT[sl * Bn + b] = e;
    }
    __syncthreads();
    red2[tid] = e;
    __syncthreads();
    for (int w = 128; w > 0; w >>= 1) { if (tid < w) red2[tid] += red2[tid + w]; __syncthreads(); }
    if (tid == 0) atomicAdd(&sumE[t * Bn + b], red2[0]);
}

// ctx[j][b] = sum_s e[s][b] * encJ[j][s][b]   (unnormalized; coalesced bf16 reads)
__global__ __launch_bounds__(256)
void dec_ctx_k(const float* __restrict__ eT, const short* __restrict__ encJ,
               float* __restrict__ ctx)
{
    const int tid = threadIdx.x;
    const int j = blockIdx.x;
    const int b = tid & 63, sq = tid >> 6;
    const short* ep = encJ + j * (Sn * Bn) + b;
    float a = 0.f;
    #pragma unroll 8
    for (int s = sq * 128; s < sq * 128 + 128; s++)
        a += eT[s * Bn + b] * bf16tof(ep[s * Bn]);
    __shared__ float red[256];
    red[tid] = a;
    __syncthreads();
    if (sq == 0) ctx[j * Bn + b] = red[b] + red[64 + b] + red[128 + b] + red[192 + b];
}

// decoder LSTM cell (zero init state: only i,g,o gates); 1/sumE folded in.
__global__ __launch_bounds__(256)
void dec_gate_k(const float* __restrict__ ctx, const float* __restrict__ sumE,
                const float* __restrict__ WiT, const float* __restrict__ WgT,
                const float* __restrict__ WoT, const float* __restrict__ dbih,
                const float* __restrict__ dbhh, float* __restrict__ hdec, int t)
{
    const int tid = threadIdx.x;
    const int b = tid & 63, kq = tid >> 6;
    const int j = blockIdx.x;
    float ai = 0.f, ag = 0.f, ao = 0.f;
    #pragma unroll 4
    for (int k = kq * 128; k < kq * 128 + 128; k++) {
        float cv = ctx[k * Bn + b];
        ai += WiT[k * Hn + j] * cv;
        ag += WgT[k * Hn + j] * cv;
        ao += WoT[k * Hn + j] * cv;
    }
    __shared__ float red[3][4][64];
    red[0][kq][b] = ai; red[1][kq][b] = ag; red[2][kq][b] = ao;
    __syncthreads();
    if (kq == 0) {
        float inv = 1.0f / sumE[t * Bn + b];
        float pi = (red[0][0][b] + red[0][1][b] + red[0][2][b] + red[0][3][b]) * inv + dbih[j] + dbhh[j];
        float pg = (red[1][0][b] + red[1][1][b] + red[1][2][b] + red[1][3][b]) * inv + dbih[2*Hn + j] + dbhh[2*Hn + j];
        float po = (red[2][0][b] + red[2][1][b] + red[2][2][b] + red[2][3][b]) * inv + dbih[3*Hn + j] + dbhh[3*Hn + j];
        float cc = sigm(pi) * tanh_f(pg);
        float hh = sigm(po) * tanh_f(cc);
        hdec[j * Bn + b] = hh;
    }
}

// final out step (t = Tn-1)
__global__ __launch_bounds__(64)
void dec_out_k(const float* __restrict__ hdec, const float* __restrict__ oW,
               const float* __restrict__ ob, float* __restrict__ out, int t)
{
    const int b = blockIdx.x;
    const int tid = threadIdx.x;
    float a = 0.f;
    #pragma unroll
    for (int q = 0; q < 8; q++) {
        int j = tid + q * 64;
        a += oW[j] * hdec[j * Bn + b];
    }
    for (int off = 32; off; off >>= 1) a += __shfl_down(a, off, 64);
    if (tid == 0) out[b * Tn + t] = a + ob[0];
}

// ============================ host ============================
extern "C" void kernel_launch(void* const* d_in, const int* in_sizes, int n_in,
                              void* d_out, int out_size, void* d_ws, size_t ws_size,
                              hipStream_t stream) {
    const float* x    = (const float*)d_in[0];
    const float* eWih = (const float*)d_in[1];
    const float* eWhh = (const float*)d_in[2];
    const float* ebih = (const float*)d_in[3];
    const float* ebhh = (const float*)d_in[4];
    const float* aW1  = (const float*)d_in[5];
    const float* ab1  = (const float*)d_in[6];
    const float* aW2  = (const float*)d_in[7];
    const float* ab2  = (const float*)d_in[8];
    const float* aV   = (const float*)d_in[9];
    const float* abV  = (const float*)d_in[10];
    const float* dWih = (const float*)d_in[11];
    // d_in[12] = dec_Whh unused (decoder starts from zero state every step)
    const float* dbih = (const float*)d_in[13];
    const float* dbhh = (const float*)d_in[14];
    const float* oW   = (const float*)d_in[15];
    const float* ob   = (const float*)d_in[16];
    float* out = (float*)d_out;

    char* wsb = (char*)d_ws;
    short* xhi    = (short*)(wsb + 0);          // 4,194,304 B
    short* xlo    = (short*)(wsb + 4194304);    // 4,194,304
    short* whhHi  = (short*)(wsb + 8388608);    // 2,097,152
    short* whhLo  = (short*)(wsb + 10485760);   // 2,097,152
    short* wihHi  = (short*)(wsb + 12582912);   // 262,144
    short* wihLo  = (short*)(wsb + 12845056);   // 262,144
    float* bperm  = (float*)(wsb + 13107200);   // 8,192
    short* W2Tb   = (short*)(wsb + 13115392);   // 131,072
    float* W1T    = (float*)(wsb + 13246464);   // 262,144
    float* WiT    = (float*)(wsb + 13508608);   // 1,048,576
    float* WgT    = (float*)(wsb + 14557184);   // 1,048,576
    float* WoT    = (float*)(wsb + 15605760);   // 1,048,576
    short* hHi    = (short*)(wsb + 16654336);   // 131,072  [2][32768]
    short* hLo    = (short*)(wsb + 16785408);   // 131,072  [2][32768]
    float* cstG   = (float*)(wsb + 16916480);   // 131,072
    short* encJ   = (short*)(wsb + 17047552);   // 33,554,432  [512][512][64] bf16
    short* w2eb   = (short*)(wsb + 50601984);   // 8,388,608   [64][512][128] bf16
    float* eT     = (float*)(wsb + 58990592);   // 131,072
    float* sumE   = (float*)(wsb + 59121664);   // 24,576
    float* ctx    = (float*)(wsb + 59146240);   // 131,072
    float* hdec   = (float*)(wsb + 59277312);   // 131,072

    // ---- setup ----
    k_split_x      <<<8192, 256, 0, stream>>>(x, xhi, xlo);
    k_split_whh    <<<4096, 256, 0, stream>>>(eWhh, whhHi, whhLo);
    k_split_wih    <<<512,  256, 0, stream>>>(eWih, wihHi, wihLo);
    k_bias_perm    <<<8,    256, 0, stream>>>(ebih, ebhh, bperm);
    k_w1t          <<<256,  256, 0, stream>>>(aW1, W1T);
    k_w2t_bf16     <<<256,  256, 0, stream>>>(aW2, W2Tb);
    k_transpose_dec<<<1024, 256, 0, stream>>>(dWih, WiT, WgT, WoT);
    k_zero_state   <<<408,  256, 0, stream>>>((float*)hHi, sumE);

    // ---- encoder: 512 per-step launches (kernel boundary = grid barrier) ----
    for (int t = 0; t < Sn; t++) {
        const int pr = t & 1, pw = 1 - pr;
        enc_step3<<<256, 512, 0, stream>>>(xhi, xlo, whhHi, whhLo, wihHi, wihLo,
                                           bperm,
                                           hHi + pr * 32768, hLo + pr * 32768,
                                           hHi + pw * 32768, hLo + pw * 32768,
                                           cstG, encJ, t);
    }

    // ---- attention hoist ----
    w2enc_k<<<512, 256, 0, stream>>>(encJ, W2Tb, ab2, w2eb);

    // ---- decoder: 3 kernels per step ----
    for (int t = 0; t < Tn; t++) {
        dec_attn_k<<<256, 256, 0, stream>>>(hdec, encJ, W1T, ab1, aV, abV, w2eb,
                                            oW, ob, eT, sumE, out, t);
        dec_ctx_k <<<512, 256, 0, stream>>>(eT, encJ, ctx);
        dec_gate_k<<<512, 256, 0, stream>>>(ctx, sumE, WiT, WgT, WoT, dbih, dbhh, hdec, t);
    }
    dec_out_k<<<64, 64, 0, stream>>>(hdec, oW, ob, out, Tn - 1);
}